// Round 1
// baseline (255.259 us; speedup 1.0000x reference)
//
#include <hip/hip_runtime.h>
#include <math.h>

#define C_S   128
#define C_HIDD 16
#define H_    12
#define P_    4
#define V_    8
#define B_    2
#define N_    512
#define BH_   (B_*H_)

// workspace offsets in floats
#define SZ_ROW  (BH_*N_)                 // 12288 (b,h,n) rows
#define OFF_Q   0
#define OFF_K   (OFF_Q  + SZ_ROW*16)
#define OFF_V   (OFF_K  + SZ_ROW*16)
#define OFF_QP  (OFF_V  + SZ_ROW*16)
#define OFF_KP  (OFF_QP + SZ_ROW*12)
#define OFF_VP  (OFF_KP + SZ_ROW*12)
#define OFF_SQQ (OFF_VP + SZ_ROW*24)
#define OFF_SQK (OFF_SQQ + SZ_ROW)
#define OFF_CAT (OFF_SQK + SZ_ROW)       // B*N*576

// ---------------------------------------------------------------------------
// Kernel A: projections + frame rotation + sq precompute.
// 4 tokens per block (weight reads amortized 4x), 256 threads.
// ---------------------------------------------------------------------------
__global__ __launch_bounds__(256) void proj_kernel(
    const float* __restrict__ s,   const float* __restrict__ Rg,
    const float* __restrict__ tg,
    const float* __restrict__ Wq,  const float* __restrict__ bq,
    const float* __restrict__ Wkv, const float* __restrict__ bkv,
    const float* __restrict__ Wqp, const float* __restrict__ bqp,
    const float* __restrict__ Wkvp,const float* __restrict__ bkvp,
    float* __restrict__ ws)
{
    __shared__ float sS[4][128];
    __shared__ float proj[4][1152];
    __shared__ float sqq[4][48];
    __shared__ float sqkb[4][144];

    const int tid  = threadIdx.x;
    const int tok0 = blockIdx.x * 4;

    for (int idx = tid; idx < 4*128; idx += 256) {
        int tk = idx >> 7, c = idx & 127;
        sS[tk][c] = s[(tok0+tk)*C_S + c];
    }
    __syncthreads();

    // features: [0,192)=q, [192,576)=kv, [576,720)=qp-lin, [720,1152)=kvp-lin
    for (int f = tid; f < 1152; f += 256) {
        const float* w; int col, od; float bias;
        if (f < 192)      { w = Wq;   col = f;      od = 192; bias = bq[col];  }
        else if (f < 576) { w = Wkv;  col = f-192;  od = 384; bias = bkv[col]; }
        else if (f < 720) { w = Wqp;  col = f-576;  od = 144; bias = bqp[col]; }
        else              { w = Wkvp; col = f-720;  od = 432; bias = bkvp[col];}
        float a0 = bias, a1 = bias, a2 = bias, a3 = bias;
        for (int c = 0; c < 128; ++c) {
            float wv = w[c*od + col];
            a0 += sS[0][c]*wv; a1 += sS[1][c]*wv;
            a2 += sS[2][c]*wv; a3 += sS[3][c]*wv;
        }
        proj[0][f] = a0; proj[1][f] = a1; proj[2][f] = a2; proj[3][f] = a3;
    }
    __syncthreads();

    const float qscale = 0.14433756729740643f;  // 1/sqrt(3*C_HID)=1/sqrt(48)

    // q -> [bh][n][16], scale folded
    for (int idx = tid; idx < 4*192; idx += 256) {
        int tk = idx/192, f = idx%192;
        int h = f >> 4, c = f & 15;
        int tok = tok0+tk, b = tok/N_, n = tok%N_;
        ws[OFF_Q + ((b*H_+h)*N_ + n)*16 + c] = proj[tk][f]*qscale;
    }
    // kv -> k,v [bh][n][16]
    for (int idx = tid; idx < 4*384; idx += 256) {
        int tk = idx/384, f = idx%384;
        int h = f >> 5, d = f & 31;
        int tok = tok0+tk, b = tok/N_, n = tok%N_;
        int row = (b*H_+h)*N_ + n;
        float val = proj[tk][192+f];
        if (d < 16) ws[OFF_K + row*16 + d]      = val;
        else        ws[OFF_V + row*16 + (d-16)] = val;
    }
    // qp: 48 points per token; x[b,n,i,p] at proj[576 + i*48 + p]
    for (int idx = tid; idx < 4*48; idx += 256) {
        int tk = idx/48, p = idx%48;
        int tok = tok0+tk, b = tok/N_, n = tok%N_;
        const float* Rr = Rg + tok*9;
        const float* tr = tg + tok*3;
        float x0 = proj[tk][576 + 0*48 + p];
        float x1 = proj[tk][576 + 1*48 + p];
        float x2 = proj[tk][576 + 2*48 + p];
        float r0 = Rr[0]*x0 + Rr[1]*x1 + Rr[2]*x2 + tr[0];
        float r1 = Rr[3]*x0 + Rr[4]*x1 + Rr[5]*x2 + tr[1];
        float r2 = Rr[6]*x0 + Rr[7]*x1 + Rr[8]*x2 + tr[2];
        int h = p >> 2, pp = p & 3;
        int row = (b*H_+h)*N_ + n;
        ws[OFF_QP + row*12 + pp*3 + 0] = r0;
        ws[OFF_QP + row*12 + pp*3 + 1] = r1;
        ws[OFF_QP + row*12 + pp*3 + 2] = r2;
        sqq[tk][p] = r0*r0 + r1*r1 + r2*r2;
    }
    // kvp: 144 points; proj[720 + i*144 + p]; pp<4 -> kp, else vp
    for (int idx = tid; idx < 4*144; idx += 256) {
        int tk = idx/144, p = idx%144;
        int tok = tok0+tk, b = tok/N_, n = tok%N_;
        const float* Rr = Rg + tok*9;
        const float* tr = tg + tok*3;
        float x0 = proj[tk][720 + 0*144 + p];
        float x1 = proj[tk][720 + 1*144 + p];
        float x2 = proj[tk][720 + 2*144 + p];
        float r0 = Rr[0]*x0 + Rr[1]*x1 + Rr[2]*x2 + tr[0];
        float r1 = Rr[3]*x0 + Rr[4]*x1 + Rr[5]*x2 + tr[1];
        float r2 = Rr[6]*x0 + Rr[7]*x1 + Rr[8]*x2 + tr[2];
        int h = p/12, pp = p%12;
        int row = (b*H_+h)*N_ + n;
        if (pp < 4) {
            ws[OFF_KP + row*12 + pp*3 + 0] = r0;
            ws[OFF_KP + row*12 + pp*3 + 1] = r1;
            ws[OFF_KP + row*12 + pp*3 + 2] = r2;
            sqkb[tk][p] = r0*r0 + r1*r1 + r2*r2;
        } else {
            int vv = pp-4;
            ws[OFF_VP + row*24 + vv*3 + 0] = r0;
            ws[OFF_VP + row*24 + vv*3 + 1] = r1;
            ws[OFF_VP + row*24 + vv*3 + 2] = r2;
        }
    }
    __syncthreads();
    // reduce sq per (token, head)
    for (int idx = tid; idx < 4*12; idx += 256) {
        int tk = idx/12, h = idx%12;
        int tok = tok0+tk, b = tok/N_, n = tok%N_;
        int row = (b*H_+h)*N_ + n;
        ws[OFF_SQQ + row] = sqq[tk][h*4+0]+sqq[tk][h*4+1]+sqq[tk][h*4+2]+sqq[tk][h*4+3];
        ws[OFF_SQK + row] = sqkb[tk][h*12+0]+sqkb[tk][h*12+1]+sqkb[tk][h*12+2]+sqkb[tk][h*12+3];
    }
}

// ---------------------------------------------------------------------------
// Kernel B: flash-style attention. Block = (b,h, 32-row i-tile), 256 threads.
// Thread (ia = tid>>3, jsub = tid&7): logits in regs, private acc[40].
// ---------------------------------------------------------------------------
__global__ __launch_bounds__(256) void attn_kernel(
    const float* __restrict__ Rg, const float* __restrict__ tg,
    const float* __restrict__ maskg, const float* __restrict__ hwg,
    float* __restrict__ ws)
{
    __shared__ __align__(16) float kb[64*28];   // k(16)+kp(12)
    __shared__ __align__(16) float vb[64*40];   // v(16)+vp(24)
    __shared__ float sqk_s[64];
    __shared__ float m_s[32], l_s[32], alpha_s[32];
    __shared__ float pbuf[32*8];
    __shared__ float obuf[32*40];

    const int tid  = threadIdx.x;
    const int bh   = blockIdx.x >> 4;   // 16 i-tiles per (b,h)
    const int it   = blockIdx.x & 15;
    const int b    = bh / H_, h = bh % H_;
    const int i0   = it * 32;
    const int ia   = tid >> 3, jsub = tid & 7;
    const int irow = i0 + ia;

    // per-thread q/qp fragments in registers (8 threads/row redundant, loaded once)
    float q_r[16], qp_r[12];
    {
        const float4* qv = (const float4*)(ws + OFF_Q + (bh*N_ + irow)*16);
        #pragma unroll
        for (int c4 = 0; c4 < 4; ++c4) {
            float4 v4 = qv[c4];
            q_r[c4*4+0]=v4.x; q_r[c4*4+1]=v4.y; q_r[c4*4+2]=v4.z; q_r[c4*4+3]=v4.w;
        }
        const float4* pv = (const float4*)(ws + OFF_QP + (bh*N_ + irow)*12);
        #pragma unroll
        for (int c4 = 0; c4 < 3; ++c4) {
            float4 v4 = pv[c4];
            qp_r[c4*4+0]=v4.x; qp_r[c4*4+1]=v4.y; qp_r[c4*4+2]=v4.z; qp_r[c4*4+3]=v4.w;
        }
    }
    const float sqq_r = ws[OFF_SQQ + bh*N_ + irow];
    const float hx = hwg[h];
    const float sp = (hx > 20.f) ? hx : log1pf(__expf(hx));
    const float c_pt = -0.5f * sp * 0.13608276348795434f;  // sqrt(1/54)

    float acc[40];
    #pragma unroll
    for (int d = 0; d < 40; ++d) acc[d] = 0.f;
    if (tid < 32) { m_s[tid] = -1e30f; l_s[tid] = 0.f; }

    for (int jt = 0; jt < 8; ++jt) {
        const int j0 = jt * 64;
        __syncthreads();  // protect kb/vb from previous tile's readers
        for (int idx = tid; idx < 64*16; idx += 256) {
            int j = idx >> 4, c = idx & 15;
            kb[j*28 + c] = ws[OFF_K + (bh*N_ + j0+j)*16 + c];
            vb[j*40 + c] = ws[OFF_V + (bh*N_ + j0+j)*16 + c];
        }
        for (int idx = tid; idx < 64*12; idx += 256) {
            int j = idx/12, c = idx%12;
            kb[j*28 + 16 + c] = ws[OFF_KP + (bh*N_ + j0+j)*12 + c];
        }
        for (int idx = tid; idx < 64*24; idx += 256) {
            int j = idx/24, c = idx%24;
            vb[j*40 + 16 + c] = ws[OFF_VP + (bh*N_ + j0+j)*24 + c];
        }
        if (tid < 64) sqk_s[tid] = ws[OFF_SQK + bh*N_ + j0 + tid];
        __syncthreads();

        // logits for this thread's 8 j's
        float lg[8];
        float tmax = -1e30f;
        #pragma unroll
        for (int jj = 0; jj < 8; ++jj) {
            int j = jsub + jj*8;
            const float* kr = kb + j*28;
            float qk = 0.f, cross = 0.f;
            #pragma unroll
            for (int c = 0; c < 16; ++c) qk += q_r[c]*kr[c];
            #pragma unroll
            for (int c = 0; c < 12; ++c) cross += qp_r[c]*kr[16+c];
            float d2 = sqq_r + sqk_s[j] - 2.f*cross;
            float mval = maskg[(b*N_ + irow)*N_ + j0 + j];
            float L = qk + c_pt*d2 + 1e5f*(mval - 1.f);
            lg[jj] = L;
            tmax = fmaxf(tmax, L);
        }
        pbuf[ia*8 + jsub] = tmax;
        __syncthreads();
        if (tid < 32) {
            float tm = pbuf[tid*8];
            #pragma unroll
            for (int k2 = 1; k2 < 8; ++k2) tm = fmaxf(tm, pbuf[tid*8+k2]);
            float mnew = fmaxf(m_s[tid], tm);
            float al = __expf(m_s[tid] - mnew);
            alpha_s[tid] = al;
            l_s[tid] *= al;
            m_s[tid] = mnew;
        }
        __syncthreads();
        const float mrow = m_s[ia];
        const float al   = alpha_s[ia];
        #pragma unroll
        for (int d = 0; d < 40; ++d) acc[d] *= al;
        float psum = 0.f;
        #pragma unroll
        for (int jj = 0; jj < 8; ++jj) {
            int j = jsub + jj*8;
            float p = __expf(lg[jj] - mrow);
            psum += p;
            const float4* vr = (const float4*)(vb + j*40);
            #pragma unroll
            for (int c4 = 0; c4 < 10; ++c4) {
                float4 v4 = vr[c4];
                acc[c4*4+0] += p*v4.x; acc[c4*4+1] += p*v4.y;
                acc[c4*4+2] += p*v4.z; acc[c4*4+3] += p*v4.w;
            }
        }
        pbuf[ia*8 + jsub] = psum;
        __syncthreads();
        if (tid < 32) {
            float sm = 0.f;
            #pragma unroll
            for (int k2 = 0; k2 < 8; ++k2) sm += pbuf[tid*8+k2];
            l_s[tid] += sm;
        }
    }
    __syncthreads();

    // reduce partial acc across the 8 jsub lanes (consecutive lanes, same wave)
    #pragma unroll
    for (int d = 0; d < 40; ++d) {
        acc[d] += __shfl_xor(acc[d], 1);
        acc[d] += __shfl_xor(acc[d], 2);
        acc[d] += __shfl_xor(acc[d], 4);
    }
    if (tid < 32) alpha_s[tid] = 1.f / l_s[tid];
    __syncthreads();
    if (jsub == 0) {
        float inv = alpha_s[ia];
        #pragma unroll
        for (int d = 0; d < 40; ++d) obuf[ia*40 + d] = acc[d]*inv;
    }
    __syncthreads();

    // epilogue: o part of cat
    for (int idx = tid; idx < 32*16; idx += 256) {
        int r = idx >> 4, c = idx & 15;
        int token = b*N_ + i0 + r;
        ws[OFF_CAT + token*576 + h*16 + c] = obuf[r*40 + c];
    }
    // points: inverse rotation R^T g - t, norm, write x/y/z/norm slices
    {
        int r = tid >> 3, pv = tid & 7;
        int token = b*N_ + i0 + r;
        const float* Rr = Rg + token*9;
        const float* tr = tg + token*3;
        float g0 = obuf[r*40 + 16 + pv*3 + 0];
        float g1 = obuf[r*40 + 16 + pv*3 + 1];
        float g2 = obuf[r*40 + 16 + pv*3 + 2];
        float lx = Rr[0]*g0 + Rr[3]*g1 + Rr[6]*g2 - tr[0];
        float ly = Rr[1]*g0 + Rr[4]*g1 + Rr[7]*g2 - tr[1];
        float lz = Rr[2]*g0 + Rr[5]*g1 + Rr[8]*g2 - tr[2];
        float nrm = sqrtf(lx*lx + ly*ly + lz*lz + 1e-8f);
        float* cat = ws + OFF_CAT + token*576;
        cat[192 + h*8 + pv] = lx;
        cat[288 + h*8 + pv] = ly;
        cat[384 + h*8 + pv] = lz;
        cat[480 + h*8 + pv] = nrm;
    }
}

// ---------------------------------------------------------------------------
// Kernel C: out = cat @ Wout + bout.  4 tokens per block, 128 threads.
// ---------------------------------------------------------------------------
__global__ __launch_bounds__(128) void out_kernel(
    const float* __restrict__ Wout, const float* __restrict__ bout,
    const float* __restrict__ ws, float* __restrict__ out)
{
    __shared__ float catS[4][576];
    const int tid  = threadIdx.x;
    const int tok0 = blockIdx.x * 4;
    for (int idx = tid; idx < 4*576; idx += 128) {
        int tk = idx / 576, c = idx % 576;
        catS[tk][c] = ws[OFF_CAT + (tok0+tk)*576 + c];
    }
    __syncthreads();
    float a0 = bout[tid], a1 = a0, a2 = a0, a3 = a0;
    for (int c = 0; c < 576; ++c) {
        float w = Wout[c*128 + tid];
        a0 += catS[0][c]*w; a1 += catS[1][c]*w;
        a2 += catS[2][c]*w; a3 += catS[3][c]*w;
    }
    out[(tok0+0)*128 + tid] = a0;
    out[(tok0+1)*128 + tid] = a1;
    out[(tok0+2)*128 + tid] = a2;
    out[(tok0+3)*128 + tid] = a3;
}

extern "C" void kernel_launch(void* const* d_in, const int* in_sizes, int n_in,
                              void* d_out, int out_size, void* d_ws, size_t ws_size,
                              hipStream_t stream) {
    const float* s    = (const float*)d_in[0];
    const float* R    = (const float*)d_in[1];
    const float* t    = (const float*)d_in[2];
    const float* mask = (const float*)d_in[3];
    const float* Wq   = (const float*)d_in[4];
    const float* bq   = (const float*)d_in[5];
    const float* Wkv  = (const float*)d_in[6];
    const float* bkv  = (const float*)d_in[7];
    const float* Wqp  = (const float*)d_in[8];
    const float* bqp  = (const float*)d_in[9];
    const float* Wkvp = (const float*)d_in[10];
    const float* bkvp = (const float*)d_in[11];
    const float* hw   = (const float*)d_in[12];
    const float* Wout = (const float*)d_in[13];
    const float* bout = (const float*)d_in[14];
    float* ws  = (float*)d_ws;
    float* out = (float*)d_out;

    proj_kernel<<<B_*N_/4, 256, 0, stream>>>(s, R, t, Wq, bq, Wkv, bkv,
                                             Wqp, bqp, Wkvp, bkvp, ws);
    attn_kernel<<<BH_*16, 256, 0, stream>>>(R, t, mask, hw, ws);
    out_kernel<<<B_*N_/4, 128, 0, stream>>>(Wout, bout, ws, out);
}

// Round 2
// 168.610 us; speedup vs baseline: 1.5139x; 1.5139x over previous
//
#include <hip/hip_runtime.h>
#include <math.h>

#define H_    12
#define B_    2
#define N_    512
#define BH_   (B_*H_)

// ws layout (floats). Packed rows:
//   Q row (per bh,n): [q*scale (16) | qp (12) | sqq | pad3]          = 32
//   K row:            [k (16)       | kp (12) | sqk | pad3]          = 32
//   V row:            [v (16)       | vp (24)]                       = 40
// PTS: point-linear gemm output, cols 576..1152 of the fused proj; dead
// after pack_kernel, so CAT overlays it.
#define OFF_Q   0
#define OFF_K   (OFF_Q + BH_*N_*32)          //  393216
#define OFF_V   (OFF_K + BH_*N_*32)          //  786432
#define OFF_PTS (OFF_V + BH_*N_*40)          // 1277952
#define OFF_CAT OFF_PTS                      // overlay (PTS dead before attn)

#define QSCALE 0.14433756729740643f          // 1/sqrt(48)

// ---------------------------------------------------------------------------
// Kernel 1: fused projection GEMM.  C[1024][1152] = s[1024][128] @ Wcat + b.
// M-tile 64, N-tile 32, K=128 fully resident. Epilogue scatters into packed
// Q/K/V layouts (cols < 576) or the PTS buffer (point linears, cols >= 576).
// grid (36 n-tiles, 16 m-tiles) x 256 threads.
// ---------------------------------------------------------------------------
__global__ __launch_bounds__(256) void gemm_proj(
    const float* __restrict__ s,
    const float* __restrict__ Wq,  const float* __restrict__ bq,
    const float* __restrict__ Wkv, const float* __restrict__ bkv,
    const float* __restrict__ Wqp, const float* __restrict__ bqp,
    const float* __restrict__ Wkvp,const float* __restrict__ bkvp,
    float* __restrict__ ws)
{
    __shared__ __align__(16) float sT[128*68];   // [k][m], pad 68 (16B-aligned rows)
    __shared__ float wT[128*32];                 // [k][n]
    __shared__ float biasS[32];

    const int tid  = threadIdx.x;
    const int nt0  = blockIdx.x * 32;   // global col base
    const int mt0  = blockIdx.y * 64;   // global row (token) base

    // stage s transposed: lanes cover m (conflict-free LDS writes)
    for (int idx = tid; idx < 2048; idx += 256) {
        int k4 = idx >> 6, m = idx & 63;
        float4 v = *(const float4*)(s + (mt0+m)*128 + k4*4);
        sT[(k4*4+0)*68 + m] = v.x;
        sT[(k4*4+1)*68 + m] = v.y;
        sT[(k4*4+2)*68 + m] = v.z;
        sT[(k4*4+3)*68 + m] = v.w;
    }
    // stage W tile (per-column matrix lookup; lanes cover cols -> coalesced)
    for (int idx = tid; idx < 4096; idx += 256) {
        int k = idx >> 5, c = idx & 31;
        int col = nt0 + c;
        const float* w; int lc, od;
        if (col < 192)      { w = Wq;   lc = col;     od = 192; }
        else if (col < 576) { w = Wkv;  lc = col-192; od = 384; }
        else if (col < 720) { w = Wqp;  lc = col-576; od = 144; }
        else                { w = Wkvp; lc = col-720; od = 432; }
        wT[k*32 + c] = w[k*od + lc];
    }
    if (tid < 32) {
        int col = nt0 + tid;
        float bv;
        if (col < 192)      bv = bq[col];
        else if (col < 576) bv = bkv[col-192];
        else if (col < 720) bv = bqp[col-576];
        else                bv = bkvp[col-720];
        biasS[tid] = bv;
    }
    __syncthreads();

    const int m0 = (tid >> 4) * 4;      // 4 rows
    const int n0 = (tid & 15) * 2;      // 2 cols
    float acc[4][2] = {};
    #pragma unroll 4
    for (int k = 0; k < 128; ++k) {
        float4 sv = *(const float4*)(sT + k*68 + m0);
        float2 wv = *(const float2*)(wT + k*32 + n0);
        acc[0][0] += sv.x*wv.x; acc[0][1] += sv.x*wv.y;
        acc[1][0] += sv.y*wv.x; acc[1][1] += sv.y*wv.y;
        acc[2][0] += sv.z*wv.x; acc[2][1] += sv.z*wv.y;
        acc[3][0] += sv.w*wv.x; acc[3][1] += sv.w*wv.y;
    }

    #pragma unroll
    for (int i = 0; i < 4; ++i) {
        #pragma unroll
        for (int jn = 0; jn < 2; ++jn) {
            int tok = mt0 + m0 + i;
            int col = nt0 + n0 + jn;
            float val = acc[i][jn] + biasS[n0 + jn];
            int b = tok >> 9, n = tok & 511;
            if (col < 192) {
                int h = col >> 4, c = col & 15;
                ws[OFF_Q + ((b*H_+h)*N_ + n)*32 + c] = val * QSCALE;
            } else if (col < 576) {
                int f = col - 192, h = f >> 5, d = f & 31;
                int row = (b*H_+h)*N_ + n;
                if (d < 16) ws[OFF_K + row*32 + d]      = val;
                else        ws[OFF_V + row*40 + (d-16)] = val;
            } else {
                ws[OFF_PTS + tok*576 + (col - 576)] = val;
            }
        }
    }
}

// ---------------------------------------------------------------------------
// Kernel 2: point rotation + packing + sq sums. 4 tokens/block, 256 threads.
// Reads PTS, writes qp/kp/vp slots + sqq/sqk into packed rows.
// ---------------------------------------------------------------------------
__global__ __launch_bounds__(256) void pack_kernel(
    const float* __restrict__ Rg, const float* __restrict__ tg,
    float* __restrict__ ws)
{
    __shared__ float ldsP[4][576];
    __shared__ float sqq[4][48];
    __shared__ float sqkb[4][144];

    const int tid  = threadIdx.x;
    const int tok0 = blockIdx.x * 4;

    for (int idx = tid; idx < 4*576; idx += 256) {
        int tk = idx / 576, c = idx % 576;
        ldsP[tk][c] = ws[OFF_PTS + (tok0+tk)*576 + c];
    }
    __syncthreads();

    // q-points: cols i*48 + p  (i = coord)
    for (int idx = tid; idx < 4*48; idx += 256) {
        int tk = idx / 48, p = idx % 48;
        int tok = tok0+tk, b = tok >> 9, n = tok & 511;
        const float* Rr = Rg + tok*9;
        const float* tr = tg + tok*3;
        float x0 = ldsP[tk][0*48 + p];
        float x1 = ldsP[tk][1*48 + p];
        float x2 = ldsP[tk][2*48 + p];
        float r0 = Rr[0]*x0 + Rr[1]*x1 + Rr[2]*x2 + tr[0];
        float r1 = Rr[3]*x0 + Rr[4]*x1 + Rr[5]*x2 + tr[1];
        float r2 = Rr[6]*x0 + Rr[7]*x1 + Rr[8]*x2 + tr[2];
        int h = p >> 2, pp = p & 3;
        int row = (b*H_+h)*N_ + n;
        ws[OFF_Q + row*32 + 16 + pp*3 + 0] = r0;
        ws[OFF_Q + row*32 + 16 + pp*3 + 1] = r1;
        ws[OFF_Q + row*32 + 16 + pp*3 + 2] = r2;
        sqq[tk][p] = r0*r0 + r1*r1 + r2*r2;
    }
    // kv-points: cols 144 + i*144 + p
    for (int idx = tid; idx < 4*144; idx += 256) {
        int tk = idx / 144, p = idx % 144;
        int tok = tok0+tk, b = tok >> 9, n = tok & 511;
        const float* Rr = Rg + tok*9;
        const float* tr = tg + tok*3;
        float x0 = ldsP[tk][144 + 0*144 + p];
        float x1 = ldsP[tk][144 + 1*144 + p];
        float x2 = ldsP[tk][144 + 2*144 + p];
        float r0 = Rr[0]*x0 + Rr[1]*x1 + Rr[2]*x2 + tr[0];
        float r1 = Rr[3]*x0 + Rr[4]*x1 + Rr[5]*x2 + tr[1];
        float r2 = Rr[6]*x0 + Rr[7]*x1 + Rr[8]*x2 + tr[2];
        int h = p / 12, pp = p % 12;
        int row = (b*H_+h)*N_ + n;
        if (pp < 4) {
            ws[OFF_K + row*32 + 16 + pp*3 + 0] = r0;
            ws[OFF_K + row*32 + 16 + pp*3 + 1] = r1;
            ws[OFF_K + row*32 + 16 + pp*3 + 2] = r2;
            sqkb[tk][p] = r0*r0 + r1*r1 + r2*r2;
        } else {
            int vv = pp - 4;
            ws[OFF_V + row*40 + 16 + vv*3 + 0] = r0;
            ws[OFF_V + row*40 + 16 + vv*3 + 1] = r1;
            ws[OFF_V + row*40 + 16 + vv*3 + 2] = r2;
        }
    }
    __syncthreads();
    for (int idx = tid; idx < 4*12; idx += 256) {
        int tk = idx / 12, h = idx % 12;
        int tok = tok0+tk, b = tok >> 9, n = tok & 511;
        int row = (b*H_+h)*N_ + n;
        ws[OFF_Q + row*32 + 28] = sqq[tk][h*4+0]+sqq[tk][h*4+1]+sqq[tk][h*4+2]+sqq[tk][h*4+3];
        ws[OFF_K + row*32 + 28] = sqkb[tk][h*12+0]+sqkb[tk][h*12+1]+sqkb[tk][h*12+2]+sqkb[tk][h*12+3];
    }
}

// ---------------------------------------------------------------------------
// Kernel 3: flash attention. Block = (bh, 16-row i-tile), 128 threads.
// Row = 8 consecutive lanes (jsub = tid&7): softmax reductions are pure
// __shfl_xor, no barriers. j-tile 128 -> 4 staging phases, 2 barriers each.
// ---------------------------------------------------------------------------
__global__ __launch_bounds__(128) void attn_kernel(
    const float* __restrict__ Rg, const float* __restrict__ tg,
    const float* __restrict__ maskg, const float* __restrict__ hwg,
    float* __restrict__ ws)
{
    __shared__ __align__(16) float kb[128*36];   // rows of 32 (k16|kp12|sqk|pad), stride 36
    __shared__ __align__(16) float vb[128*44];   // rows of 40 (v16|vp24), stride 44

    const int tid  = threadIdx.x;
    const int bh   = blockIdx.x >> 5;   // 32 i-tiles per (b,h)
    const int it   = blockIdx.x & 31;
    const int b    = bh / H_, h = bh % H_;
    const int i0   = it * 16;
    const int ia   = tid >> 3, jsub = tid & 7;
    const int irow = i0 + ia;

    float q_r[16], qp_r[12], sqq_r;
    {
        const float4* qrow = (const float4*)(ws + OFF_Q + (bh*N_ + irow)*32);
        #pragma unroll
        for (int c4 = 0; c4 < 4; ++c4) {
            float4 v4 = qrow[c4];
            q_r[c4*4+0]=v4.x; q_r[c4*4+1]=v4.y; q_r[c4*4+2]=v4.z; q_r[c4*4+3]=v4.w;
        }
        #pragma unroll
        for (int c4 = 0; c4 < 3; ++c4) {
            float4 v4 = qrow[4+c4];
            qp_r[c4*4+0]=v4.x; qp_r[c4*4+1]=v4.y; qp_r[c4*4+2]=v4.z; qp_r[c4*4+3]=v4.w;
        }
        sqq_r = ((const float*)qrow)[28];
    }
    const float hx = hwg[h];
    const float sp = (hx > 20.f) ? hx : log1pf(__expf(hx));
    const float c_pt = -0.5f * sp * 0.13608276348795434f;  // sqrt(1/54)

    float acc[40];
    #pragma unroll
    for (int d = 0; d < 40; ++d) acc[d] = 0.f;
    float m_run = -1e30f, l_run = 0.f;

    for (int jt = 0; jt < 4; ++jt) {
        const int j0 = jt * 128;
        __syncthreads();   // protect kb/vb from previous tile's readers
        for (int idx = tid; idx < 1024; idx += 128) {     // K rows: 8 f4 each
            int j = idx >> 3, c4 = idx & 7;
            float4 v4 = *(const float4*)(ws + OFF_K + (bh*N_ + j0+j)*32 + c4*4);
            *(float4*)(kb + j*36 + c4*4) = v4;
        }
        for (int idx = tid; idx < 1280; idx += 128) {     // V rows: 10 f4 each
            int j = idx / 10, c4 = idx % 10;
            float4 v4 = *(const float4*)(ws + OFF_V + (bh*N_ + j0+j)*40 + c4*4);
            *(float4*)(vb + j*44 + c4*4) = v4;
        }
        __syncthreads();

        float lg[16];
        float tmax = -1e30f;
        #pragma unroll
        for (int jj = 0; jj < 16; ++jj) {
            int j = jsub + jj*8;
            const float4* kr = (const float4*)(kb + j*36);
            float4 k0 = kr[0], k1 = kr[1], k2 = kr[2], k3 = kr[3];
            float qk = q_r[0]*k0.x + q_r[1]*k0.y + q_r[2]*k0.z + q_r[3]*k0.w
                     + q_r[4]*k1.x + q_r[5]*k1.y + q_r[6]*k1.z + q_r[7]*k1.w
                     + q_r[8]*k2.x + q_r[9]*k2.y + q_r[10]*k2.z + q_r[11]*k2.w
                     + q_r[12]*k3.x + q_r[13]*k3.y + q_r[14]*k3.z + q_r[15]*k3.w;
            float4 k4v = kr[4], k5 = kr[5], k6 = kr[6];
            float cross = qp_r[0]*k4v.x + qp_r[1]*k4v.y + qp_r[2]*k4v.z + qp_r[3]*k4v.w
                        + qp_r[4]*k5.x  + qp_r[5]*k5.y  + qp_r[6]*k5.z  + qp_r[7]*k5.w
                        + qp_r[8]*k6.x  + qp_r[9]*k6.y  + qp_r[10]*k6.z + qp_r[11]*k6.w;
            float sqk = kb[j*36 + 28];
            float d2 = sqq_r + sqk - 2.f*cross;
            float mval = maskg[(b*N_ + irow)*N_ + j0 + j];
            float L = qk + c_pt*d2 + 1e5f*(mval - 1.f);
            lg[jj] = L;
            tmax = fmaxf(tmax, L);
        }
        // row max across the 8 jsub lanes
        tmax = fmaxf(tmax, __shfl_xor(tmax, 1));
        tmax = fmaxf(tmax, __shfl_xor(tmax, 2));
        tmax = fmaxf(tmax, __shfl_xor(tmax, 4));
        float mnew = fmaxf(m_run, tmax);
        float al = __expf(m_run - mnew);
        m_run = mnew;
        #pragma unroll
        for (int d = 0; d < 40; ++d) acc[d] *= al;
        l_run *= al;
        float psum = 0.f;
        #pragma unroll
        for (int jj = 0; jj < 16; ++jj) {
            int j = jsub + jj*8;
            float p = __expf(lg[jj] - mnew);
            psum += p;
            const float4* vr = (const float4*)(vb + j*44);
            #pragma unroll
            for (int c4 = 0; c4 < 10; ++c4) {
                float4 v4 = vr[c4];
                acc[c4*4+0] += p*v4.x; acc[c4*4+1] += p*v4.y;
                acc[c4*4+2] += p*v4.z; acc[c4*4+3] += p*v4.w;
            }
        }
        l_run += psum;
    }

    // reduce across the 8 jsub lanes
    #pragma unroll
    for (int d = 0; d < 40; ++d) {
        acc[d] += __shfl_xor(acc[d], 1);
        acc[d] += __shfl_xor(acc[d], 2);
        acc[d] += __shfl_xor(acc[d], 4);
    }
    l_run += __shfl_xor(l_run, 1);
    l_run += __shfl_xor(l_run, 2);
    l_run += __shfl_xor(l_run, 4);
    const float inv = 1.f / l_run;

    __syncthreads();
    float* obuf = kb;   // reuse
    if (jsub == 0) {
        #pragma unroll
        for (int d = 0; d < 40; ++d) obuf[ia*40 + d] = acc[d]*inv;
    }
    __syncthreads();

    // epilogue: o part of cat (16 rows x 16 ch, 2 per thread)
    for (int idx = tid; idx < 256; idx += 128) {
        int r = idx >> 4, c = idx & 15;
        int token = b*N_ + i0 + r;
        ws[OFF_CAT + token*576 + h*16 + c] = obuf[r*40 + c];
    }
    // points: R^T g - t, norm
    {
        int r = tid >> 3, pv = tid & 7;
        int token = b*N_ + i0 + r;
        const float* Rr = Rg + token*9;
        const float* tr = tg + token*3;
        float g0 = obuf[r*40 + 16 + pv*3 + 0];
        float g1 = obuf[r*40 + 16 + pv*3 + 1];
        float g2 = obuf[r*40 + 16 + pv*3 + 2];
        float lx = Rr[0]*g0 + Rr[3]*g1 + Rr[6]*g2 - tr[0];
        float ly = Rr[1]*g0 + Rr[4]*g1 + Rr[7]*g2 - tr[1];
        float lz = Rr[2]*g0 + Rr[5]*g1 + Rr[8]*g2 - tr[2];
        float nrm = sqrtf(lx*lx + ly*ly + lz*lz + 1e-8f);
        float* cat = ws + OFF_CAT + token*576;
        cat[192 + h*8 + pv] = lx;
        cat[288 + h*8 + pv] = ly;
        cat[384 + h*8 + pv] = lz;
        cat[480 + h*8 + pv] = nrm;
    }
}

// ---------------------------------------------------------------------------
// Kernel 4: out = cat @ Wout + bout.  Tiled GEMM M16 x N32, K=576 (3 chunks).
// grid 64 m-tiles x 4 n-tiles = 256 blocks x 256 threads.
// ---------------------------------------------------------------------------
__global__ __launch_bounds__(256) void out_kernel(
    const float* __restrict__ Wout, const float* __restrict__ bout,
    const float* __restrict__ ws, float* __restrict__ out)
{
    __shared__ float catT[192*20];              // [k][m], stride 20
    __shared__ __align__(16) float wT2[192*36]; // [k][n], stride 36

    const int tid  = threadIdx.x;
    const int nt0  = (blockIdx.x & 3) * 32;
    const int tok0 = (blockIdx.x >> 2) * 16;
    const int m    = tid >> 4;
    const int n0   = (tid & 15) * 2;

    float a0 = 0.f, a1 = 0.f;
    for (int kc = 0; kc < 3; ++kc) {
        const int k0 = kc * 192;
        __syncthreads();
        for (int idx = tid; idx < 768; idx += 256) {   // cat: 16 m x 48 f4
            int mm = idx & 15, k4 = idx >> 4;
            float4 v4 = *(const float4*)(ws + OFF_CAT + (tok0+mm)*576 + k0 + k4*4);
            catT[(k4*4+0)*20 + mm] = v4.x;
            catT[(k4*4+1)*20 + mm] = v4.y;
            catT[(k4*4+2)*20 + mm] = v4.z;
            catT[(k4*4+3)*20 + mm] = v4.w;
        }
        for (int idx = tid; idx < 1536; idx += 256) {  // W: 192 k x 8 f4
            int k = idx >> 3, n4 = idx & 7;
            float4 v4 = *(const float4*)(Wout + (k0+k)*128 + nt0 + n4*4);
            *(float4*)(wT2 + k*36 + n4*4) = v4;
        }
        __syncthreads();
        #pragma unroll 4
        for (int k = 0; k < 192; ++k) {
            float cv = catT[k*20 + m];
            float2 wv = *(const float2*)(wT2 + k*36 + n0);
            a0 += cv*wv.x;
            a1 += cv*wv.y;
        }
    }
    out[(tok0+m)*128 + nt0 + n0 + 0] = a0 + bout[nt0 + n0 + 0];
    out[(tok0+m)*128 + nt0 + n0 + 1] = a1 + bout[nt0 + n0 + 1];
}

extern "C" void kernel_launch(void* const* d_in, const int* in_sizes, int n_in,
                              void* d_out, int out_size, void* d_ws, size_t ws_size,
                              hipStream_t stream) {
    const float* s    = (const float*)d_in[0];
    const float* R    = (const float*)d_in[1];
    const float* t    = (const float*)d_in[2];
    const float* mask = (const float*)d_in[3];
    const float* Wq   = (const float*)d_in[4];
    const float* bq   = (const float*)d_in[5];
    const float* Wkv  = (const float*)d_in[6];
    const float* bkv  = (const float*)d_in[7];
    const float* Wqp  = (const float*)d_in[8];
    const float* bqp  = (const float*)d_in[9];
    const float* Wkvp = (const float*)d_in[10];
    const float* bkvp = (const float*)d_in[11];
    const float* hw   = (const float*)d_in[12];
    const float* Wout = (const float*)d_in[13];
    const float* bout = (const float*)d_in[14];
    float* ws  = (float*)d_ws;
    float* out = (float*)d_out;

    gemm_proj<<<dim3(36, 16), 256, 0, stream>>>(s, Wq, bq, Wkv, bkv,
                                                Wqp, bqp, Wkvp, bkvp, ws);
    pack_kernel<<<B_*N_/4, 256, 0, stream>>>(R, t, ws);
    attn_kernel<<<BH_*32, 128, 0, stream>>>(R, t, mask, hw, ws);
    out_kernel<<<256, 256, 0, stream>>>(Wout, bout, ws, out);
}

// Round 3
// 145.698 us; speedup vs baseline: 1.7520x; 1.1573x over previous
//
#include <hip/hip_runtime.h>
#include <hip/hip_bf16.h>
#include <math.h>

#define H_    12
#define B_    2
#define N_    512
#define BH_   (B_*H_)
#define QSCALE 0.14433756729740643f          // 1/sqrt(48)
#define CPT_K  0.13608276348795434f          // sqrt(1/54)

// ws layout (float units)
#define OFF_RAW 0                            // [1024][1152] f32 (dead after pack)
#define OFF_CAT 0                            // overlay of RAW
#define OFF_QB  1179648                      // bf16 [bh][512][32]
#define OFF_KB  1376256                      // bf16 [bh][512][32]
#define OFF_VT  1572864                      // bf16 [bh][40][512]
#define OFF_SA  1818624                      // f32  [bh*512]
#define OFF_SB  1830912                      // f32  [bh*512]

typedef __attribute__((ext_vector_type(8))) short sh8;
typedef __attribute__((ext_vector_type(4))) float f32x4;
typedef unsigned short u16t;

static __device__ __forceinline__ u16t f2b(float x) {
    __hip_bfloat16 h = __float2bfloat16(x);
    return *reinterpret_cast<u16t*>(&h);
}

// ---------------------------------------------------------------------------
// Kernel 1: fused projection GEMM -> raw[tok][1152] fp32 (bias folded).
// ---------------------------------------------------------------------------
__global__ __launch_bounds__(256) void gemm_proj(
    const float* __restrict__ s,
    const float* __restrict__ Wq,  const float* __restrict__ bq,
    const float* __restrict__ Wkv, const float* __restrict__ bkv,
    const float* __restrict__ Wqp, const float* __restrict__ bqp,
    const float* __restrict__ Wkvp,const float* __restrict__ bkvp,
    float* __restrict__ ws)
{
    __shared__ __align__(16) float sT[128*68];
    __shared__ float wT[128*32];
    __shared__ float biasS[32];

    const int tid  = threadIdx.x;
    const int nt0  = blockIdx.x * 32;
    const int mt0  = blockIdx.y * 64;

    for (int idx = tid; idx < 2048; idx += 256) {
        int k4 = idx >> 6, m = idx & 63;
        float4 v = *(const float4*)(s + (mt0+m)*128 + k4*4);
        sT[(k4*4+0)*68 + m] = v.x;
        sT[(k4*4+1)*68 + m] = v.y;
        sT[(k4*4+2)*68 + m] = v.z;
        sT[(k4*4+3)*68 + m] = v.w;
    }
    for (int idx = tid; idx < 4096; idx += 256) {
        int k = idx >> 5, c = idx & 31;
        int col = nt0 + c;
        const float* w; int lc, od;
        if (col < 192)      { w = Wq;   lc = col;     od = 192; }
        else if (col < 576) { w = Wkv;  lc = col-192; od = 384; }
        else if (col < 720) { w = Wqp;  lc = col-576; od = 144; }
        else                { w = Wkvp; lc = col-720; od = 432; }
        wT[k*32 + c] = w[k*od + lc];
    }
    if (tid < 32) {
        int col = nt0 + tid;
        float bv;
        if (col < 192)      bv = bq[col];
        else if (col < 576) bv = bkv[col-192];
        else if (col < 720) bv = bqp[col-576];
        else                bv = bkvp[col-720];
        biasS[tid] = bv;
    }
    __syncthreads();

    const int m0 = (tid >> 4) * 4;
    const int n0 = (tid & 15) * 2;
    float acc[4][2] = {};
    #pragma unroll 4
    for (int k = 0; k < 128; ++k) {
        float4 sv = *(const float4*)(sT + k*68 + m0);
        float2 wv = *(const float2*)(wT + k*32 + n0);
        acc[0][0] += sv.x*wv.x; acc[0][1] += sv.x*wv.y;
        acc[1][0] += sv.y*wv.x; acc[1][1] += sv.y*wv.y;
        acc[2][0] += sv.z*wv.x; acc[2][1] += sv.z*wv.y;
        acc[3][0] += sv.w*wv.x; acc[3][1] += sv.w*wv.y;
    }
    float* raw = ws + OFF_RAW;
    #pragma unroll
    for (int i = 0; i < 4; ++i) {
        int tok = mt0 + m0 + i;
        float2 o;
        o.x = acc[i][0] + biasS[n0+0];
        o.y = acc[i][1] + biasS[n0+1];
        *(float2*)(raw + tok*1152 + nt0 + n0) = o;
    }
}

// ---------------------------------------------------------------------------
// Kernel 2: rotations + bf16 packing.
// Qb[bh][n][32] = [q*qscale | qp_rot*(-2c_pt) | 0000] bf16
// Kb[bh][n][32] = [k        | kp_rot          | 0000] bf16
// Vt[bh][40][512] = V' transposed, bf16.  sa/sb = c_pt*sqq / c_pt*sqk fp32.
// ---------------------------------------------------------------------------
__global__ __launch_bounds__(256) void pack_kernel(
    const float* __restrict__ Rg, const float* __restrict__ tg,
    const float* __restrict__ hwg, float* __restrict__ ws)
{
    __shared__ float ldsP[4][1152];
    __shared__ float rotQ[4][48][3];
    __shared__ float rotK[4][48][3];
    __shared__ float rotV[4][96][3];

    const float* raw = ws + OFF_RAW;
    u16t* Qb = (u16t*)(ws + OFF_QB);
    u16t* Kb = (u16t*)(ws + OFF_KB);
    u16t* Vt = (u16t*)(ws + OFF_VT);
    float* sa_g = ws + OFF_SA;
    float* sb_g = ws + OFF_SB;

    const int tid  = threadIdx.x;
    const int tok0 = blockIdx.x * 4;
    const int b    = tok0 >> 9, n0 = tok0 & 511;

    for (int idx = tid; idx < 1152; idx += 256) {
        int tk = idx / 288, c4 = idx % 288;
        *(float4*)&ldsP[tk][c4*4] = *(const float4*)(raw + (tok0+tk)*1152 + c4*4);
    }
    __syncthreads();

    for (int idx = tid; idx < 4*48; idx += 256) {
        int tk = idx / 48, p = idx % 48;
        int tok = tok0 + tk;
        const float* Rr = Rg + tok*9;
        const float* tr = tg + tok*3;
        float x0 = ldsP[tk][576 +   0 + p];
        float x1 = ldsP[tk][576 +  48 + p];
        float x2 = ldsP[tk][576 +  96 + p];
        rotQ[tk][p][0] = Rr[0]*x0 + Rr[1]*x1 + Rr[2]*x2 + tr[0];
        rotQ[tk][p][1] = Rr[3]*x0 + Rr[4]*x1 + Rr[5]*x2 + tr[1];
        rotQ[tk][p][2] = Rr[6]*x0 + Rr[7]*x1 + Rr[8]*x2 + tr[2];
    }
    for (int idx = tid; idx < 4*144; idx += 256) {
        int tk = idx / 144, p = idx % 144;
        int tok = tok0 + tk;
        const float* Rr = Rg + tok*9;
        const float* tr = tg + tok*3;
        float x0 = ldsP[tk][720 +   0 + p];
        float x1 = ldsP[tk][720 + 144 + p];
        float x2 = ldsP[tk][720 + 288 + p];
        float r0 = Rr[0]*x0 + Rr[1]*x1 + Rr[2]*x2 + tr[0];
        float r1 = Rr[3]*x0 + Rr[4]*x1 + Rr[5]*x2 + tr[1];
        float r2 = Rr[6]*x0 + Rr[7]*x1 + Rr[8]*x2 + tr[2];
        int h = p / 12, pp = p % 12;
        if (pp < 4) {
            rotK[tk][h*4+pp][0] = r0; rotK[tk][h*4+pp][1] = r1; rotK[tk][h*4+pp][2] = r2;
        } else {
            rotV[tk][h*8+pp-4][0] = r0; rotV[tk][h*8+pp-4][1] = r1; rotV[tk][h*8+pp-4][2] = r2;
        }
    }
    __syncthreads();

    // Qb / Kb: idx over (sel, tok, h, half)
    for (int idx = tid; idx < 192; idx += 256) {
        int sel = idx / 96, rem = idx % 96;
        int tk = rem / 24, r2 = rem % 24, h = r2 >> 1, half = r2 & 1;
        float hx = hwg[h];
        float sp = (hx > 20.f) ? hx : log1pf(__expf(hx));
        float c_pt = -0.5f * sp * CPT_K;
        union { sh8 v[2]; u16t u[16]; } pk;
        if (sel == 0) {  // Qb
            if (half == 0) {
                #pragma unroll
                for (int e = 0; e < 16; ++e) pk.u[e] = f2b(ldsP[tk][h*16 + e] * QSCALE);
            } else {
                float qs = -2.f * c_pt;
                #pragma unroll
                for (int e = 0; e < 12; ++e) pk.u[e] = f2b(rotQ[tk][h*4 + e/3][e%3] * qs);
                pk.u[12]=0; pk.u[13]=0; pk.u[14]=0; pk.u[15]=0;
            }
            u16t* dst = Qb + ((b*H_+h)*N_ + n0 + tk)*32 + half*16;
            *(sh8*)dst = pk.v[0];
            *(sh8*)(dst+8) = pk.v[1];
        } else {         // Kb
            if (half == 0) {
                #pragma unroll
                for (int e = 0; e < 16; ++e) pk.u[e] = f2b(ldsP[tk][192 + h*32 + e]);
            } else {
                #pragma unroll
                for (int e = 0; e < 12; ++e) pk.u[e] = f2b(rotK[tk][h*4 + e/3][e%3]);
                pk.u[12]=0; pk.u[13]=0; pk.u[14]=0; pk.u[15]=0;
            }
            u16t* dst = Kb + ((b*H_+h)*N_ + n0 + tk)*32 + half*16;
            *(sh8*)dst = pk.v[0];
            *(sh8*)(dst+8) = pk.v[1];
        }
    }
    // Vt: idx over (h,d): 480 tasks, 4 tokens each -> 8B store
    for (int idx = tid; idx < 480; idx += 256) {
        int h = idx / 40, d = idx % 40;
        union { uint2 v; u16t u[4]; } pk;
        #pragma unroll
        for (int tk = 0; tk < 4; ++tk) {
            float val;
            if (d < 16) val = ldsP[tk][192 + h*32 + 16 + d];
            else        val = rotV[tk][h*8 + (d-16)/3][(d-16)%3];
            pk.u[tk] = f2b(val);
        }
        *(uint2*)(Vt + ((b*H_+h)*40 + d)*N_ + n0) = pk.v;
    }
    // sa / sb: idx over (tok,h)
    for (int idx = tid; idx < 48; idx += 256) {
        int tk = idx / 12, h = idx % 12;
        float hx = hwg[h];
        float sp = (hx > 20.f) ? hx : log1pf(__expf(hx));
        float c_pt = -0.5f * sp * CPT_K;
        float sq = 0.f, sk = 0.f;
        #pragma unroll
        for (int pp = 0; pp < 4; ++pp) {
            #pragma unroll
            for (int c = 0; c < 3; ++c) {
                float a = rotQ[tk][h*4+pp][c]; sq += a*a;
                float k = rotK[tk][h*4+pp][c]; sk += k*k;
            }
        }
        sa_g[(b*H_+h)*N_ + n0 + tk] = c_pt * sq;
        sb_g[(b*H_+h)*N_ + n0 + tk] = c_pt * sk;
    }
}

// ---------------------------------------------------------------------------
// Kernel 3: MFMA flash attention. Block = (bh, 64-row i-tile), 4 waves.
// Wave w owns rows [i0+16w, i0+16w+16). j-tiles of 64: 4 QK + 6 PV MFMAs.
// ---------------------------------------------------------------------------
__global__ __launch_bounds__(256) void attn_kernel(
    const float* __restrict__ Rg, const float* __restrict__ tg,
    const float* __restrict__ maskg, float* __restrict__ ws)
{
    __shared__ __align__(16) char smem[21504];
    u16t* smK  = (u16t*)smem;            // 64 rows x 40 (data 32)   5120 B
    u16t* smV  = smK + 2560;             // 48 rows x 72 (data 64)   6912 B
    u16t* smP  = smV + 3456;             // 4 waves x 16 x 72        9216 B
    float* smSb = (float*)(smP + 4608);  // 64 f32                    256 B
    float* obuf = (float*)smem;          // overlay: 64 x 48 f32    12288 B

    const u16t* Qb = (const u16t*)(ws + OFF_QB);
    const u16t* Kb = (const u16t*)(ws + OFF_KB);
    const u16t* Vt = (const u16t*)(ws + OFF_VT);
    const float* sa_g = ws + OFF_SA;
    const float* sb_g = ws + OFF_SB;

    const int tid  = threadIdx.x;
    const int w    = tid >> 6, lane = tid & 63;
    const int q    = lane >> 4, lx = lane & 15;
    const int bh   = blockIdx.x >> 3;
    const int it   = blockIdx.x & 7;
    const int b    = bh / H_, h = bh % H_;
    const int i0   = it * 64;

    sh8 qfrag = *(const sh8*)(Qb + ((bh*N_ + i0 + w*16 + lx)*32 + q*8));
    float sa_r[4];
    #pragma unroll
    for (int r = 0; r < 4; ++r)
        sa_r[r] = sa_g[bh*N_ + i0 + w*16 + q*4 + r];

    float m_run[4] = {-1e30f,-1e30f,-1e30f,-1e30f};
    float l_run[4] = {0.f,0.f,0.f,0.f};
    f32x4 oc0 = {0.f,0.f,0.f,0.f}, oc1 = oc0, oc2 = oc0;

    // zero V' pad rows 40..47 (persist across tiles; staging writes rows<40)
    {
        int row = 40 + (tid >> 5), cu = tid & 31;
        *(unsigned int*)(smV + row*72 + cu*2) = 0u;
    }

    const float* mrow = maskg + (size_t)(b*N_ + i0 + w*16 + q*4)*N_ + lx;

    for (int jt = 0; jt < 8; ++jt) {
        const int j0 = jt * 64;
        __syncthreads();
        {   // K' staging: 256 chunks of 16B
            int j = tid >> 2, c = tid & 3;
            *(sh8*)(smK + j*40 + c*8) = *(const sh8*)(Kb + (bh*N_ + j0 + j)*32 + c*8);
        }
        for (int idx = tid; idx < 320; idx += 256) {   // Vt: 40 rows x 8 chunks
            int d = idx >> 3, c = idx & 7;
            *(sh8*)(smV + d*72 + c*8) = *(const sh8*)(Vt + (bh*40 + d)*N_ + j0 + c*8);
        }
        if (tid < 64) smSb[tid] = sb_g[bh*N_ + j0 + tid];
        __syncthreads();

        float mb[16];
        #pragma unroll
        for (int r = 0; r < 4; ++r)
            #pragma unroll
            for (int st = 0; st < 4; ++st)
                mb[r*4+st] = mrow[r*N_ + j0 + st*16];

        f32x4 sc[4];
        #pragma unroll
        for (int st = 0; st < 4; ++st) {
            sh8 kf = *(const sh8*)(smK + (st*16 + lx)*40 + q*8);
            f32x4 z = {0.f,0.f,0.f,0.f};
            sc[st] = __builtin_amdgcn_mfma_f32_16x16x32_bf16(qfrag, kf, z, 0, 0, 0);
        }
        float sbv[4];
        #pragma unroll
        for (int st = 0; st < 4; ++st) sbv[st] = smSb[st*16 + lx];

        float L[16];
        #pragma unroll
        for (int st = 0; st < 4; ++st)
            #pragma unroll
            for (int r = 0; r < 4; ++r)
                L[st*4+r] = sc[st][r] + sa_r[r] + sbv[st] + 1e5f*(mb[r*4+st] - 1.f);

        #pragma unroll
        for (int r = 0; r < 4; ++r) {
            float tm = fmaxf(fmaxf(L[0*4+r], L[1*4+r]), fmaxf(L[2*4+r], L[3*4+r]));
            tm = fmaxf(tm, __shfl_xor(tm, 1));
            tm = fmaxf(tm, __shfl_xor(tm, 2));
            tm = fmaxf(tm, __shfl_xor(tm, 4));
            tm = fmaxf(tm, __shfl_xor(tm, 8));
            float mnew = fmaxf(m_run[r], tm);
            float al = __expf(m_run[r] - mnew);
            m_run[r] = mnew;
            l_run[r] *= al;
            oc0[r] *= al; oc1[r] *= al; oc2[r] *= al;
        }
        u16t* pw = smP + w*1152;
        #pragma unroll
        for (int st = 0; st < 4; ++st)
            #pragma unroll
            for (int r = 0; r < 4; ++r) {
                float p = __expf(L[st*4+r] - m_run[r]);
                l_run[r] += p;
                pw[(q*4+r)*72 + st*16 + lx] = f2b(p);
            }
        const u16t* pr = smP + w*1152;
        #pragma unroll
        for (int c = 0; c < 2; ++c) {
            sh8 pa = *(const sh8*)(pr + lx*72 + c*32 + q*8);
            sh8 v0 = *(const sh8*)(smV + ( 0 + lx)*72 + c*32 + q*8);
            sh8 v1 = *(const sh8*)(smV + (16 + lx)*72 + c*32 + q*8);
            sh8 v2 = *(const sh8*)(smV + (32 + lx)*72 + c*32 + q*8);
            oc0 = __builtin_amdgcn_mfma_f32_16x16x32_bf16(pa, v0, oc0, 0, 0, 0);
            oc1 = __builtin_amdgcn_mfma_f32_16x16x32_bf16(pa, v1, oc1, 0, 0, 0);
            oc2 = __builtin_amdgcn_mfma_f32_16x16x32_bf16(pa, v2, oc2, 0, 0, 0);
        }
    }

    float linv[4];
    #pragma unroll
    for (int r = 0; r < 4; ++r) {
        float l = l_run[r];
        l += __shfl_xor(l, 1); l += __shfl_xor(l, 2);
        l += __shfl_xor(l, 4); l += __shfl_xor(l, 8);
        linv[r] = 1.f / l;
    }
    __syncthreads();   // all waves done reading smK/smV/smP
    #pragma unroll
    for (int r = 0; r < 4; ++r) {
        int row = w*16 + q*4 + r;
        obuf[row*48 +  0 + lx] = oc0[r] * linv[r];
        obuf[row*48 + 16 + lx] = oc1[r] * linv[r];
        obuf[row*48 + 32 + lx] = oc2[r] * linv[r];
    }
    __syncthreads();

    // epilogue: o part
    for (int idx = tid; idx < 1024; idx += 256) {
        int r = idx >> 4, c = idx & 15;
        int token = b*N_ + i0 + r;
        ws[OFF_CAT + token*576 + h*16 + c] = obuf[r*48 + c];
    }
    // points: R^T g - t, norm
    for (int idx = tid; idx < 512; idx += 256) {
        int r = idx >> 3, pv = idx & 7;
        int token = b*N_ + i0 + r;
        const float* Rr = Rg + token*9;
        const float* tr = tg + token*3;
        float g0 = obuf[r*48 + 16 + pv*3 + 0];
        float g1 = obuf[r*48 + 16 + pv*3 + 1];
        float g2 = obuf[r*48 + 16 + pv*3 + 2];
        float lx2 = Rr[0]*g0 + Rr[3]*g1 + Rr[6]*g2 - tr[0];
        float ly  = Rr[1]*g0 + Rr[4]*g1 + Rr[7]*g2 - tr[1];
        float lz  = Rr[2]*g0 + Rr[5]*g1 + Rr[8]*g2 - tr[2];
        float nrm = sqrtf(lx2*lx2 + ly*ly + lz*lz + 1e-8f);
        float* cat = ws + OFF_CAT + token*576;
        cat[192 + h*8 + pv] = lx2;
        cat[288 + h*8 + pv] = ly;
        cat[384 + h*8 + pv] = lz;
        cat[480 + h*8 + pv] = nrm;
    }
}

// ---------------------------------------------------------------------------
// Kernel 4: out = cat @ Wout + bout. (unchanged tiled GEMM)
// ---------------------------------------------------------------------------
__global__ __launch_bounds__(256) void out_kernel(
    const float* __restrict__ Wout, const float* __restrict__ bout,
    const float* __restrict__ ws, float* __restrict__ out)
{
    __shared__ float catT[192*20];
    __shared__ __align__(16) float wT2[192*36];

    const int tid  = threadIdx.x;
    const int nt0  = (blockIdx.x & 3) * 32;
    const int tok0 = (blockIdx.x >> 2) * 16;
    const int m    = tid >> 4;
    const int n0   = (tid & 15) * 2;

    float a0 = 0.f, a1 = 0.f;
    for (int kc = 0; kc < 3; ++kc) {
        const int k0 = kc * 192;
        __syncthreads();
        for (int idx = tid; idx < 768; idx += 256) {
            int mm = idx & 15, k4 = idx >> 4;
            float4 v4 = *(const float4*)(ws + OFF_CAT + (tok0+mm)*576 + k0 + k4*4);
            catT[(k4*4+0)*20 + mm] = v4.x;
            catT[(k4*4+1)*20 + mm] = v4.y;
            catT[(k4*4+2)*20 + mm] = v4.z;
            catT[(k4*4+3)*20 + mm] = v4.w;
        }
        for (int idx = tid; idx < 1536; idx += 256) {
            int k = idx >> 3, n4 = idx & 7;
            float4 v4 = *(const float4*)(Wout + (k0+k)*128 + nt0 + n4*4);
            *(float4*)(wT2 + k*36 + n4*4) = v4;
        }
        __syncthreads();
        #pragma unroll 4
        for (int k = 0; k < 192; ++k) {
            float cv = catT[k*20 + m];
            float2 wv = *(const float2*)(wT2 + k*36 + n0);
            a0 += cv*wv.x;
            a1 += cv*wv.y;
        }
    }
    out[(tok0+m)*128 + nt0 + n0 + 0] = a0 + bout[nt0 + n0 + 0];
    out[(tok0+m)*128 + nt0 + n0 + 1] = a1 + bout[nt0 + n0 + 1];
}

extern "C" void kernel_launch(void* const* d_in, const int* in_sizes, int n_in,
                              void* d_out, int out_size, void* d_ws, size_t ws_size,
                              hipStream_t stream) {
    const float* s    = (const float*)d_in[0];
    const float* R    = (const float*)d_in[1];
    const float* t    = (const float*)d_in[2];
    const float* mask = (const float*)d_in[3];
    const float* Wq   = (const float*)d_in[4];
    const float* bq   = (const float*)d_in[5];
    const float* Wkv  = (const float*)d_in[6];
    const float* bkv  = (const float*)d_in[7];
    const float* Wqp  = (const float*)d_in[8];
    const float* bqp  = (const float*)d_in[9];
    const float* Wkvp = (const float*)d_in[10];
    const float* bkvp = (const float*)d_in[11];
    const float* hw   = (const float*)d_in[12];
    const float* Wout = (const float*)d_in[13];
    const float* bout = (const float*)d_in[14];
    float* ws  = (float*)d_ws;
    float* out = (float*)d_out;

    gemm_proj<<<dim3(36, 16), 256, 0, stream>>>(s, Wq, bq, Wkv, bkv,
                                                Wqp, bqp, Wkvp, bkvp, ws);
    pack_kernel<<<B_*N_/4, 256, 0, stream>>>(R, t, hw, ws);
    attn_kernel<<<BH_*8, 256, 0, stream>>>(R, t, mask, ws);
    out_kernel<<<256, 256, 0, stream>>>(Wout, bout, ws, out);
}

// Round 5
// 113.986 us; speedup vs baseline: 2.2394x; 1.2782x over previous
//
#include <hip/hip_runtime.h>
#include <hip/hip_bf16.h>
#include <math.h>

#define H_    12
#define B_    2
#define N_    512
#define BH_   (B_*H_)
#define QSCALE 0.14433756729740643f          // 1/sqrt(48)
#define CPT_K  0.13608276348795434f          // sqrt(1/54)

// ---------------- ws layout (float units) ----------------
#define OFF_RAW  0                           // f32 [1024][1152]
#define OFF_APK  1179648                     // bf16 s-packed   [16mt][4ks][4kq][64m][8]
#define OFF_WPP  1245184                     // bf16 Wproj-pack [18nt][4ks][4kq][64n][8]
#define OFF_WOP  1318912                     // bf16 Wout-pack  [2nt][18ks][4kq][64n][8]
#define OFF_BIA  1355776                     // f32 fused bias [1152]
#define OFF_QB   1356928                     // bf16 [bh][512][32]
#define OFF_KP   1553536                     // bf16 [bh][32jt][4kq][16j][8]
#define OFF_VP   1750144                     // bf16 [bh][16jt32][3nq][4kq][16n][8j]
#define OFF_SA   2045056                     // f32 [bh*512]
#define OFF_SB   2057344                     // f32 [bh*512]
#define OFF_CATP 2069632                     // bf16 [64mt][18ks][4kq][16m][8]

typedef __attribute__((ext_vector_type(8))) short sh8;
typedef __attribute__((ext_vector_type(4))) float f32x4;
typedef unsigned short u16t;

static __device__ __forceinline__ u16t f2b(float x) {
    __hip_bfloat16 h = __float2bfloat16(x);
    return *reinterpret_cast<u16t*>(&h);
}
static __device__ __forceinline__ int catp_idx(int tok, int col) {
    return (tok >> 4)*9216 + (col >> 5)*512 + ((col >> 3) & 3)*128
         + (tok & 15)*8 + (col & 7);
}

// ---------------------------------------------------------------------------
// Kernel 0: pack s, Wproj, Wout into MFMA-fragment-ordered bf16 images + bias.
// sh8-unit task ranges: [0,16384) Apack, [16384,34816) Wproj,
// [34816,44032) Wout (9216 = 2nt*18ks*4kq*64n), [44032,45184) bias floats.
// ---------------------------------------------------------------------------
__global__ __launch_bounds__(256) void convert_kernel(
    const float* __restrict__ s,
    const float* __restrict__ Wq,  const float* __restrict__ bq,
    const float* __restrict__ Wkv, const float* __restrict__ bkv,
    const float* __restrict__ Wqp, const float* __restrict__ bqp,
    const float* __restrict__ Wkvp,const float* __restrict__ bkvp,
    const float* __restrict__ Wout, float* __restrict__ ws)
{
    const int g = blockIdx.x * 256 + threadIdx.x;
    union { sh8 v; u16t u[8]; } pk;

    if (g < 16384) {                       // s-packed
        int u = g;
        int m = u & 63, kq = (u >> 6) & 3, ks = (u >> 8) & 3, mt = u >> 10;
        int tok = mt*64 + m, k0 = ks*32 + kq*8;
        const float* src = s + tok*128 + k0;
        #pragma unroll
        for (int j = 0; j < 8; ++j) pk.u[j] = f2b(src[j]);
        *((sh8*)((u16t*)(ws + OFF_APK)) + u) = pk.v;
    } else if (g < 34816) {                // Wproj-packed
        int u = g - 16384;
        int n = u & 63, kq = (u >> 6) & 3, ks = (u >> 8) & 3, nt = u >> 10;
        int col = nt*64 + n, k0 = ks*32 + kq*8;
        const float* w; int lc, od;
        if (col < 192)      { w = Wq;   lc = col;     od = 192; }
        else if (col < 576) { w = Wkv;  lc = col-192; od = 384; }
        else if (col < 720) { w = Wqp;  lc = col-576; od = 144; }
        else                { w = Wkvp; lc = col-720; od = 432; }
        #pragma unroll
        for (int j = 0; j < 8; ++j) pk.u[j] = f2b(w[(k0+j)*od + lc]);
        *((sh8*)((u16t*)(ws + OFF_WPP)) + u) = pk.v;
    } else if (g < 44032) {                // Wout-packed (9216 frags)
        int u = g - 34816;
        int n = u & 63, kq = (u >> 6) & 3, rem = u >> 8;   // rem in [0,36)
        int ks = rem % 18, nt = rem / 18;
        int col = nt*64 + n, k0 = ks*32 + kq*8;
        #pragma unroll
        for (int j = 0; j < 8; ++j) pk.u[j] = f2b(Wout[(k0+j)*128 + col]);
        *((sh8*)((u16t*)(ws + OFF_WOP)) + u) = pk.v;
    } else if (g < 45184) {                // fused bias
        int col = g - 44032;
        float bv;
        if (col < 192)      bv = bq[col];
        else if (col < 576) bv = bkv[col-192];
        else if (col < 720) bv = bqp[col-576];
        else                bv = bkvp[col-720];
        ws[OFF_BIA + col] = bv;
    }
}

// ---------------------------------------------------------------------------
// Kernel 1: proj GEMM, no LDS. grid (18 nt, 16 mt) x 256. Wave w: rows
// mt*64+w*16..+16, cols nt*64..+64 (4 accs). K=128: 4 ksteps x 4 MFMAs.
// ---------------------------------------------------------------------------
__global__ __launch_bounds__(256) void gemm_proj(float* __restrict__ ws)
{
    const int tid = threadIdx.x;
    const int w = tid >> 6, lane = tid & 63;
    const int lx = lane & 15, kq = lane >> 4;
    const int nt = blockIdx.x, mt = blockIdx.y;

    const sh8* Ap = (const sh8*)((const u16t*)(ws + OFF_APK));
    const sh8* Bp = (const sh8*)((const u16t*)(ws + OFF_WPP));

    f32x4 acc[4];
    #pragma unroll
    for (int nq = 0; nq < 4; ++nq) acc[nq] = (f32x4){0.f,0.f,0.f,0.f};

    #pragma unroll
    for (int ks = 0; ks < 4; ++ks) {
        sh8 af = Ap[((mt*4 + ks)*4 + kq)*64 + w*16 + lx];
        #pragma unroll
        for (int nq = 0; nq < 4; ++nq) {
            sh8 bf = Bp[((nt*4 + ks)*4 + kq)*64 + nq*16 + lx];
            acc[nq] = __builtin_amdgcn_mfma_f32_16x16x32_bf16(af, bf, acc[nq], 0, 0, 0);
        }
    }
    float* raw = ws + OFF_RAW;
    const float* bias = ws + OFF_BIA;
    #pragma unroll
    for (int nq = 0; nq < 4; ++nq) {
        int col = nt*64 + nq*16 + lx;
        float bv = bias[col];
        #pragma unroll
        for (int r = 0; r < 4; ++r) {
            int tok = mt*64 + w*16 + kq*4 + r;   // C row = (lane>>4)*4 + r
            raw[tok*1152 + col] = acc[nq][r] + bv;
        }
    }
}

// ---------------------------------------------------------------------------
// Kernel 2: rotations + frag-layout bf16 packing.
// ---------------------------------------------------------------------------
__global__ __launch_bounds__(256) void pack_kernel(
    const float* __restrict__ Rg, const float* __restrict__ tg,
    const float* __restrict__ hwg, float* __restrict__ ws)
{
    __shared__ float ldsP[4][1152];
    __shared__ float rotQ[4][48][3];
    __shared__ float rotK[4][48][3];
    __shared__ float rotV[4][96][3];

    const float* raw = ws + OFF_RAW;
    u16t* Qb = (u16t*)(ws + OFF_QB);
    u16t* Kp = (u16t*)(ws + OFF_KP);
    u16t* Vp = (u16t*)(ws + OFF_VP);
    float* sa_g = ws + OFF_SA;
    float* sb_g = ws + OFF_SB;

    const int tid  = threadIdx.x;
    const int tok0 = blockIdx.x * 4;
    const int b    = tok0 >> 9, n0 = tok0 & 511;

    for (int idx = tid; idx < 1152; idx += 256) {
        int tk = idx / 288, c4 = idx % 288;
        *(float4*)&ldsP[tk][c4*4] = *(const float4*)(raw + (tok0+tk)*1152 + c4*4);
    }
    __syncthreads();

    for (int idx = tid; idx < 4*48; idx += 256) {
        int tk = idx / 48, p = idx % 48;
        int tok = tok0 + tk;
        const float* Rr = Rg + tok*9;
        const float* tr = tg + tok*3;
        float x0 = ldsP[tk][576 +   0 + p];
        float x1 = ldsP[tk][576 +  48 + p];
        float x2 = ldsP[tk][576 +  96 + p];
        rotQ[tk][p][0] = Rr[0]*x0 + Rr[1]*x1 + Rr[2]*x2 + tr[0];
        rotQ[tk][p][1] = Rr[3]*x0 + Rr[4]*x1 + Rr[5]*x2 + tr[1];
        rotQ[tk][p][2] = Rr[6]*x0 + Rr[7]*x1 + Rr[8]*x2 + tr[2];
    }
    for (int idx = tid; idx < 4*144; idx += 256) {
        int tk = idx / 144, p = idx % 144;
        int tok = tok0 + tk;
        const float* Rr = Rg + tok*9;
        const float* tr = tg + tok*3;
        float x0 = ldsP[tk][720 +   0 + p];
        float x1 = ldsP[tk][720 + 144 + p];
        float x2 = ldsP[tk][720 + 288 + p];
        float r0 = Rr[0]*x0 + Rr[1]*x1 + Rr[2]*x2 + tr[0];
        float r1 = Rr[3]*x0 + Rr[4]*x1 + Rr[5]*x2 + tr[1];
        float r2 = Rr[6]*x0 + Rr[7]*x1 + Rr[8]*x2 + tr[2];
        int h = p / 12, pp = p % 12;
        if (pp < 4) {
            rotK[tk][h*4+pp][0] = r0; rotK[tk][h*4+pp][1] = r1; rotK[tk][h*4+pp][2] = r2;
        } else {
            rotV[tk][h*8+pp-4][0] = r0; rotV[tk][h*8+pp-4][1] = r1; rotV[tk][h*8+pp-4][2] = r2;
        }
    }
    __syncthreads();

    // Qb rows : tasks (tok,h,half)
    for (int idx = tid; idx < 96; idx += 256) {
        int tk = idx / 24, r2 = idx % 24, h = r2 >> 1, half = r2 & 1;
        float hx = hwg[h];
        float sp = (hx > 20.f) ? hx : log1pf(__expf(hx));
        float c_pt = -0.5f * sp * CPT_K;
        union { sh8 v[2]; u16t u[16]; } pk;
        if (half == 0) {
            #pragma unroll
            for (int e = 0; e < 16; ++e) pk.u[e] = f2b(ldsP[tk][h*16 + e] * QSCALE);
        } else {
            float qs = -2.f * c_pt;
            #pragma unroll
            for (int e = 0; e < 12; ++e) pk.u[e] = f2b(rotQ[tk][h*4 + e/3][e%3] * qs);
            pk.u[12]=0; pk.u[13]=0; pk.u[14]=0; pk.u[15]=0;
        }
        u16t* dst = Qb + ((b*H_+h)*N_ + n0 + tk)*32 + half*16;
        *(sh8*)dst = pk.v[0];
        *(sh8*)(dst+8) = pk.v[1];
    }
    // Kp: frag-packed [bh][jt16][kq][j16][8] : tasks (tok,h,kq)
    for (int idx = tid; idx < 192; idx += 256) {
        int tk = idx / 48, r2 = idx % 48, h = r2 >> 2, kq = r2 & 3;
        int j = n0 + tk, bh = b*H_ + h;
        union { sh8 v; u16t u[8]; } pk;
        #pragma unroll
        for (int e = 0; e < 8; ++e) {
            int c = kq*8 + e;
            float val;
            if (c < 16)      val = ldsP[tk][192 + h*32 + c];
            else if (c < 28) val = rotK[tk][h*4 + (c-16)/3][(c-16)%3];
            else             val = 0.f;
            pk.u[e] = f2b(val);
        }
        *(sh8*)(Kp + bh*16384 + (j>>4)*512 + kq*128 + (j&15)*8) = pk.v;
    }
    // Vp: frag-packed [bh][jt32][nq][kq][n16][8j] : tasks (h,d), 4 tokens each
    for (int idx = tid; idx < 480; idx += 256) {
        int h = idx / 40, d = idx % 40;
        int bh = b*H_ + h;
        #pragma unroll
        for (int tk = 0; tk < 4; ++tk) {
            int j = n0 + tk;
            float val;
            if (d < 16) val = ldsP[tk][192 + h*32 + 16 + d];
            else        val = rotV[tk][h*8 + (d-16)/3][(d-16)%3];
            Vp[bh*24576 + (j>>5)*1536 + (d>>4)*512 + ((j>>3)&3)*128
               + (d&15)*8 + (j&7)] = f2b(val);
        }
    }
    // sa/sb
    for (int idx = tid; idx < 48; idx += 256) {
        int tk = idx / 12, h = idx % 12;
        float hx = hwg[h];
        float sp = (hx > 20.f) ? hx : log1pf(__expf(hx));
        float c_pt = -0.5f * sp * CPT_K;
        float sq = 0.f, sk = 0.f;
        #pragma unroll
        for (int pp = 0; pp < 4; ++pp)
            #pragma unroll
            for (int c = 0; c < 3; ++c) {
                float a = rotQ[tk][h*4+pp][c]; sq += a*a;
                float k = rotK[tk][h*4+pp][c]; sk += k*k;
            }
        sa_g[(b*H_+h)*N_ + n0 + tk] = c_pt * sq;
        sb_g[(b*H_+h)*N_ + n0 + tk] = c_pt * sk;
    }
}

// ---------------------------------------------------------------------------
// Kernel 3: MFMA flash attention, barrier-free K-loop (frags direct from
// global; only P round-trips wave-private LDS). Block = (bh, 64-row i-tile).
// ---------------------------------------------------------------------------
__global__ __launch_bounds__(256) void attn_kernel(
    const float* __restrict__ Rg, const float* __restrict__ tg,
    const float* __restrict__ maskg, float* __restrict__ ws)
{
    __shared__ u16t smP[4*16*72];     // per-wave P tiles (stride 72)
    __shared__ float obuf[4*16*32];   // per-wave point-coords (cols 16..48)

    const u16t* Qb = (const u16t*)(ws + OFF_QB);
    const u16t* Kp = (const u16t*)(ws + OFF_KP);
    const u16t* Vp = (const u16t*)(ws + OFF_VP);
    const float* sa_g = ws + OFF_SA;
    const float* sb_g = ws + OFF_SB;
    u16t* catp = (u16t*)(ws + OFF_CATP);

    const int tid  = threadIdx.x;
    const int w    = tid >> 6, lane = tid & 63;
    const int kq   = lane >> 4, lx = lane & 15;
    const int bh   = blockIdx.x >> 3;
    const int it   = blockIdx.x & 7;
    const int b    = bh / H_, h = bh % H_;
    const int i0   = it * 64;

    sh8 qfrag = *(const sh8*)(Qb + (bh*N_ + i0 + w*16 + lx)*32 + kq*8);
    float sa_r[4];
    #pragma unroll
    for (int r = 0; r < 4; ++r)
        sa_r[r] = sa_g[bh*N_ + i0 + w*16 + kq*4 + r];

    float m_run[4] = {-1e30f,-1e30f,-1e30f,-1e30f};
    float l_run[4] = {0.f,0.f,0.f,0.f};
    f32x4 oc0 = {0.f,0.f,0.f,0.f}, oc1 = oc0, oc2 = oc0;

    const float* mrow = maskg + (size_t)(b*N_ + i0 + w*16 + kq*4)*N_ + lx;
    u16t* pw = smP + w*1152;

    for (int jt = 0; jt < 8; ++jt) {
        const int j0 = jt * 64;

        f32x4 sc[4];
        #pragma unroll
        for (int st = 0; st < 4; ++st) {
            sh8 kf = *(const sh8*)(Kp + bh*16384 + (jt*4+st)*512 + kq*128 + lx*8);
            f32x4 z = {0.f,0.f,0.f,0.f};
            sc[st] = __builtin_amdgcn_mfma_f32_16x16x32_bf16(qfrag, kf, z, 0, 0, 0);
        }
        float sbv[4];
        #pragma unroll
        for (int st = 0; st < 4; ++st) sbv[st] = sb_g[bh*N_ + j0 + st*16 + lx];
        float mb[16];
        #pragma unroll
        for (int r = 0; r < 4; ++r)
            #pragma unroll
            for (int st = 0; st < 4; ++st)
                mb[r*4+st] = mrow[r*N_ + j0 + st*16];

        float L[16];
        #pragma unroll
        for (int st = 0; st < 4; ++st)
            #pragma unroll
            for (int r = 0; r < 4; ++r)
                L[st*4+r] = sc[st][r] + sa_r[r] + sbv[st] + 1e5f*(mb[r*4+st] - 1.f);

        #pragma unroll
        for (int r = 0; r < 4; ++r) {
            float tm = fmaxf(fmaxf(L[0*4+r], L[1*4+r]), fmaxf(L[2*4+r], L[3*4+r]));
            tm = fmaxf(tm, __shfl_xor(tm, 1));
            tm = fmaxf(tm, __shfl_xor(tm, 2));
            tm = fmaxf(tm, __shfl_xor(tm, 4));
            tm = fmaxf(tm, __shfl_xor(tm, 8));
            float mnew = fmaxf(m_run[r], tm);
            float al = __expf(m_run[r] - mnew);
            m_run[r] = mnew;
            l_run[r] *= al;
            oc0[r] *= al; oc1[r] *= al; oc2[r] *= al;
        }
        #pragma unroll
        for (int st = 0; st < 4; ++st)
            #pragma unroll
            for (int r = 0; r < 4; ++r) {
                float p = __expf(L[st*4+r] - m_run[r]);
                l_run[r] += p;
                pw[(kq*4+r)*72 + st*16 + lx] = f2b(p);
            }
        #pragma unroll
        for (int c = 0; c < 2; ++c) {
            sh8 pa = *(const sh8*)(pw + lx*72 + c*32 + kq*8);
            #pragma unroll
            for (int nq = 0; nq < 3; ++nq) {
                sh8 vf = *(const sh8*)(Vp + bh*24576 + (jt*2+c)*1536 + nq*512
                                        + kq*128 + lx*8);
                if (nq == 0) oc0 = __builtin_amdgcn_mfma_f32_16x16x32_bf16(pa, vf, oc0, 0,0,0);
                if (nq == 1) oc1 = __builtin_amdgcn_mfma_f32_16x16x32_bf16(pa, vf, oc1, 0,0,0);
                if (nq == 2) oc2 = __builtin_amdgcn_mfma_f32_16x16x32_bf16(pa, vf, oc2, 0,0,0);
            }
        }
    }

    float linv[4];
    #pragma unroll
    for (int r = 0; r < 4; ++r) {
        float l = l_run[r];
        l += __shfl_xor(l, 1); l += __shfl_xor(l, 2);
        l += __shfl_xor(l, 4); l += __shfl_xor(l, 8);
        linv[r] = 1.f / l;
    }

    // o part -> CAT-packed (bf16), points -> obuf (per-wave)
    #pragma unroll
    for (int r = 0; r < 4; ++r) {
        int tok = b*N_ + i0 + w*16 + kq*4 + r;
        catp[catp_idx(tok, h*16 + lx)] = f2b(oc0[r] * linv[r]);
        obuf[(w*16 + kq*4 + r)*32 + lx]      = oc1[r] * linv[r];
        obuf[(w*16 + kq*4 + r)*32 + 16 + lx] = oc2[r] * linv[r];
    }
    __syncthreads();

    // points: R^T g - t, norm; wave handles its own 16 rows x 8 pts
    #pragma unroll
    for (int tsk = 0; tsk < 2; ++tsk) {
        int task = lane + tsk*64;
        int r = task >> 3, pv = task & 7;
        int tok = b*N_ + i0 + w*16 + r;
        const float* Rr = Rg + tok*9;
        const float* tr = tg + tok*3;
        float g0 = obuf[(w*16 + r)*32 + pv*3 + 0];
        float g1 = obuf[(w*16 + r)*32 + pv*3 + 1];
        float g2 = obuf[(w*16 + r)*32 + pv*3 + 2];
        float px = Rr[0]*g0 + Rr[3]*g1 + Rr[6]*g2 - tr[0];
        float py = Rr[1]*g0 + Rr[4]*g1 + Rr[7]*g2 - tr[1];
        float pz = Rr[2]*g0 + Rr[5]*g1 + Rr[8]*g2 - tr[2];
        float nrm = sqrtf(px*px + py*py + pz*pz + 1e-8f);
        catp[catp_idx(tok, 192 + h*8 + pv)] = f2b(px);
        catp[catp_idx(tok, 288 + h*8 + pv)] = f2b(py);
        catp[catp_idx(tok, 384 + h*8 + pv)] = f2b(pz);
        catp[catp_idx(tok, 480 + h*8 + pv)] = f2b(nrm);
    }
}

// ---------------------------------------------------------------------------
// Kernel 4: out GEMM, no LDS. grid (2 nt, 64 mt) x 256. Wave w: cols
// nt*64+w*16..+16, rows mt*16..+16. K=576: 18 ksteps x 1 MFMA.
// ---------------------------------------------------------------------------
__global__ __launch_bounds__(256) void out_kernel(
    const float* __restrict__ bout, const float* __restrict__ ws,
    float* __restrict__ out)
{
    const int tid = threadIdx.x;
    const int w = tid >> 6, lane = tid & 63;
    const int lx = lane & 15, kq = lane >> 4;
    const int nt = blockIdx.x, mt = blockIdx.y;

    const sh8* Ap = (const sh8*)((const u16t*)(ws + OFF_CATP));
    const sh8* Bp = (const sh8*)((const u16t*)(ws + OFF_WOP));

    f32x4 acc = {0.f,0.f,0.f,0.f};
    for (int ks = 0; ks < 18; ++ks) {
        sh8 af = Ap[((mt*18 + ks)*4 + kq)*16 + lx];
        sh8 bf = Bp[((nt*18 + ks)*4 + kq)*64 + w*16 + lx];
        acc = __builtin_amdgcn_mfma_f32_16x16x32_bf16(af, bf, acc, 0, 0, 0);
    }
    int col = nt*64 + w*16 + lx;
    float bv = bout[col];
    #pragma unroll
    for (int r = 0; r < 4; ++r) {
        int row = mt*16 + kq*4 + r;
        out[row*128 + col] = acc[r] + bv;
    }
}

extern "C" void kernel_launch(void* const* d_in, const int* in_sizes, int n_in,
                              void* d_out, int out_size, void* d_ws, size_t ws_size,
                              hipStream_t stream) {
    const float* s    = (const float*)d_in[0];
    const float* R    = (const float*)d_in[1];
    const float* t    = (const float*)d_in[2];
    const float* mask = (const float*)d_in[3];
    const float* Wq   = (const float*)d_in[4];
    const float* bq   = (const float*)d_in[5];
    const float* Wkv  = (const float*)d_in[6];
    const float* bkv  = (const float*)d_in[7];
    const float* Wqp  = (const float*)d_in[8];
    const float* bqp  = (const float*)d_in[9];
    const float* Wkvp = (const float*)d_in[10];
    const float* bkvp = (const float*)d_in[11];
    const float* hw   = (const float*)d_in[12];
    const float* Wout = (const float*)d_in[13];
    const float* bout = (const float*)d_in[14];
    float* ws  = (float*)d_ws;
    float* out = (float*)d_out;

    convert_kernel<<<177, 256, 0, stream>>>(s, Wq, bq, Wkv, bkv,
                                            Wqp, bqp, Wkvp, bkvp, Wout, ws);
    gemm_proj<<<dim3(18, 16), 256, 0, stream>>>(ws);
    pack_kernel<<<B_*N_/4, 256, 0, stream>>>(R, t, hw, ws);
    attn_kernel<<<BH_*8, 256, 0, stream>>>(R, t, mask, ws);
    out_kernel<<<dim3(2, 64), 256, 0, stream>>>(bout, ws, out);
}